// Round 8
// baseline (336.206 us; speedup 1.0000x reference)
//
#include <hip/hip_runtime.h>
#include <cstdint>
#include <cstddef>

#define D_     256
#define TWO_D  512
#define R_     16
#define N0_    8192
#define L_     6
#define NL_    8192
#define B_     512
#define TOTAL_ (N0_ + L_*NL_)

#define MT      32          // nodes (M) per block -> 256 blocks (1/CU)
#define XPITCH  536         // ushort pitch; dword stride 268 = 12 mod 32 (conflict-free b128)
#define HPITCH  280         // ushort pitch; dword stride 140 = 12 mod 32
#define GRID_   256
#define NBAR    8

using short8 = __attribute__((ext_vector_type(8))) short;   // 8 bf16 (4 VGPRs)
using f32x4  = __attribute__((ext_vector_type(4))) float;   // 4 fp32 acc

__device__ __forceinline__ unsigned short f2bf(float f) {
    union { float f; unsigned u; } v; v.f = f;
    unsigned u = v.u;
    return (unsigned short)((u + 0x7FFFu + ((u >> 16) & 1u)) >> 16);  // RNE
}
__device__ __forceinline__ float bf2f(unsigned short h) {
    union { unsigned u; float f; } v; v.u = ((unsigned)h) << 16;
    return v.f;
}
__device__ __forceinline__ float softplus_f(float x) {
    return fmaxf(x, 0.0f) + log1pf(expf(-fabsf(x)));
}

// Device-scope single-use grid barrier (slots zeroed by wimg_k dispatches).
// 256 blocks x 512 thr = 1 block/CU -> all resident -> deadlock-free.
// (Pattern correctness-validated in round 3: absmax 0.)
__device__ __forceinline__ void grid_barrier(unsigned* bar, int idx) {
    __syncthreads();
    if (threadIdx.x == 0) {
        __threadfence();                       // release (drain stores, wb L2)
        atomicAdd(&bar[idx], 1u);
        while (__hip_atomic_load(&bar[idx], __ATOMIC_RELAXED,
                                 __HIP_MEMORY_SCOPE_AGENT) < GRID_) {
            __builtin_amdgcn_s_sleep(1);
        }
        __threadfence();                       // acquire (invalidate)
    }
    __syncthreads();
}

// ---------------------------------------------------------------- prep ----
// W [r][K][256] fp32 -> fragment image [r][ks][q][n][8] bf16:
// img(r,ks,q,n,j) = W[r][ks*32+q*8+j][n]. A wave's B-fragment load is then
// 4x256B contiguous runs (16 fully-used lines/instr). Also zeroes bar+accum.
__global__ void wimg_k(const float* __restrict__ W,
                       unsigned short* __restrict__ img,
                       int KS, float* __restrict__ accum,
                       unsigned* __restrict__ bar) {
    if (blockIdx.x == 0 && threadIdx.x < NBAR) {
        bar[threadIdx.x] = 0u;
        accum[threadIdx.x] = 0.0f;
    }
    int r  = blockIdx.x / KS;
    int ks = blockIdx.x - r * KS;
    const float* src = W + (size_t)r * KS * 32 * 256;
    #pragma unroll
    for (int it = 0; it < 4; ++it) {
        int item = it * 256 + threadIdx.x;      // 0..1023 = 4q x 256n
        int q = item >> 8, n = item & 255;
        short8 v;
        #pragma unroll
        for (int j = 0; j < 8; ++j)
            v[j] = (short)f2bf(src[(size_t)(ks * 32 + q * 8 + j) * 256 + n]);
        *(short8*)(img + ((((size_t)r * KS + ks) * 4 + q) * 256 + n) * 8) = v;
    }
}

// ------------------------------------------------------- fused persistent --
// 256 blocks x 512 threads (8 waves; wave w owns n-slice [w*32,w*32+32)).
// Each wave preloads ALL its W1/W2 B-fragments (48 frags = 192 VGPR) ONCE;
// the 6-layer loop then has zero weight traffic. Rule<->XCD swizzle.
__global__ __launch_bounds__(512, 2)
void fused_k(const int* __restrict__ thax,
             const float* __restrict__ table,
             unsigned short* __restrict__ storeb,
             const int* __restrict__ par_all,          // [L][NL][2]
             const unsigned short* __restrict__ w1img, // [R][16][4][256][8]
             const unsigned short* __restrict__ w2img, // [R][8][4][256][8]
             const float* __restrict__ b1,
             const float* __restrict__ b2,
             const float* __restrict__ eval_w,
             const float* __restrict__ eval_b,
             const float* __restrict__ pos_vals,
             const float* __restrict__ neg_vals,
             const float* __restrict__ pos_weight,
             float* __restrict__ accum,
             unsigned* __restrict__ bar,
             float* __restrict__ out) {
    __shared__ unsigned short X[MT * XPITCH];   // 34304 B
    __shared__ unsigned short H[MT * HPITCH];   // 17920 B
    __shared__ float sh[8];

    int bid = blockIdx.x;
    int tid = threadIdx.x;
    int r   = (bid & 7) | (((bid >> 3) & 1) << 3);   // XCD-local rule
    int mt  = bid >> 4;
    int nodeInLayer0 = r * B_ + mt * MT;

    int w    = tid >> 6;        // wave 0..7 -> n-slice base w*32
    int lane = tid & 63;
    int q    = lane >> 4;
    int ml   = lane & 15;
    int nb   = w * 32;

    const unsigned short* w1r = w1img + (size_t)r * 16 * 4 * 256 * 8;
    const unsigned short* w2r = w2img + (size_t)r * 8 * 4 * 256 * 8;
    size_t fb = (size_t)(q * 256 + nb + ml) * 8;   // per-lane fragment base

    // ---- one-time: preload ALL B-fragments into registers ----
    short8 w1f[32];     // [ks][ni]  (128 VGPR)
    short8 w2f[16];     // [ks][ni]  ( 64 VGPR)
    #pragma unroll
    for (int ks = 0; ks < 16; ++ks) {
        w1f[ks * 2 + 0] = *(const short8*)(&w1r[fb + (size_t)ks * 8192]);
        w1f[ks * 2 + 1] = *(const short8*)(&w1r[fb + (size_t)ks * 8192 + 128]);
    }
    #pragma unroll
    for (int ks = 0; ks < 8; ++ks) {
        w2f[ks * 2 + 0] = *(const short8*)(&w2r[fb + (size_t)ks * 8192]);
        w2f[ks * 2 + 1] = *(const short8*)(&w2r[fb + (size_t)ks * 8192 + 128]);
    }
    float bias1[2], bias2[2];
    #pragma unroll
    for (int ni = 0; ni < 2; ++ni) {
        bias1[ni] = b1[r * D_ + nb + ni * 16 + ml];
        bias2[ni] = b2[r * D_ + nb + ni * 16 + ml];
    }

    // ---- phase 0: init gather (rows [bid*32, bid*32+32)) ----
    {
        int row0 = bid * 32;
        #pragma unroll
        for (int it = 0; it < 4; ++it) {
            int e   = it * 512 + tid;          // 0..2047
            int row = row0 + (e >> 6);
            int c   = (e & 63) * 4;
            int t   = thax[row];
            float4 v = *(const float4*)(table + (size_t)t * D_ + c);
            ushort4 o;
            o.x = f2bf(v.x); o.y = f2bf(v.y); o.z = f2bf(v.z); o.w = f2bf(v.w);
            *(ushort4*)(storeb + (size_t)row * D_ + c) = o;
        }
    }
    grid_barrier(bar, 0);

    // ---- phases 1..6: layers (zero weight traffic) ----
    for (int l = 0; l < L_; ++l) {
        const int* par = par_all + (size_t)l * NL_ * 2;

        // gather parents -> X
        int pidx[4];
        #pragma unroll
        for (int it = 0; it < 4; ++it) {
            int c = it * 512 + tid;
            pidx[it] = par[(nodeInLayer0 + (c >> 6)) * 2 + ((c & 63) >> 5)];
        }
        #pragma unroll
        for (int it = 0; it < 4; ++it) {
            int c   = it * 512 + tid;
            int m   = c >> 6;
            int rem = c & 63;
            int j   = rem >> 5;
            int c16 = rem & 31;
            uint4 v = *((const uint4*)(storeb + (size_t)pidx[it] * D_) + c16);
            *((uint4*)(&X[m * XPITCH + j * D_ + c16 * 8])) = v;
        }
        __syncthreads();

        // GEMM1: [32 x 512] @ [512 x 256] -> H, relu(.+b1)
        f32x4 acc[2][2] = {};
        #pragma unroll
        for (int ks = 0; ks < 16; ++ks) {
            int k0 = ks * 32 + q * 8;
            short8 a0 = *(const short8*)(&X[ml * XPITCH + k0]);
            short8 a1 = *(const short8*)(&X[(16 + ml) * XPITCH + k0]);
            acc[0][0] = __builtin_amdgcn_mfma_f32_16x16x32_bf16(a0, w1f[ks*2+0], acc[0][0], 0, 0, 0);
            acc[1][0] = __builtin_amdgcn_mfma_f32_16x16x32_bf16(a1, w1f[ks*2+0], acc[1][0], 0, 0, 0);
            acc[0][1] = __builtin_amdgcn_mfma_f32_16x16x32_bf16(a0, w1f[ks*2+1], acc[0][1], 0, 0, 0);
            acc[1][1] = __builtin_amdgcn_mfma_f32_16x16x32_bf16(a1, w1f[ks*2+1], acc[1][1], 0, 0, 0);
        }
        #pragma unroll
        for (int ni = 0; ni < 2; ++ni) {
            int n = nb + ni * 16 + ml;
            #pragma unroll
            for (int mi = 0; mi < 2; ++mi)
                #pragma unroll
                for (int v = 0; v < 4; ++v) {
                    int row = mi * 16 + q * 4 + v;   // C/D: row = quad*4+reg
                    float x = acc[mi][ni][v] + bias1[ni];
                    H[row * HPITCH + n] = f2bf(x > 0.0f ? x : 0.0f);
                }
        }
        __syncthreads();

        // GEMM2: [32 x 256] @ [256 x 256] (+b2) -> direct global stores
        f32x4 acc2[2][2] = {};
        #pragma unroll
        for (int ks = 0; ks < 8; ++ks) {
            int k0 = ks * 32 + q * 8;
            short8 a0 = *(const short8*)(&H[ml * HPITCH + k0]);
            short8 a1 = *(const short8*)(&H[(16 + ml) * HPITCH + k0]);
            acc2[0][0] = __builtin_amdgcn_mfma_f32_16x16x32_bf16(a0, w2f[ks*2+0], acc2[0][0], 0, 0, 0);
            acc2[1][0] = __builtin_amdgcn_mfma_f32_16x16x32_bf16(a1, w2f[ks*2+0], acc2[1][0], 0, 0, 0);
            acc2[0][1] = __builtin_amdgcn_mfma_f32_16x16x32_bf16(a0, w2f[ks*2+1], acc2[0][1], 0, 0, 0);
            acc2[1][1] = __builtin_amdgcn_mfma_f32_16x16x32_bf16(a1, w2f[ks*2+1], acc2[1][1], 0, 0, 0);
        }
        size_t outBase = (size_t)(N0_ + l * NL_ + nodeInLayer0);
        #pragma unroll
        for (int ni = 0; ni < 2; ++ni) {
            int n = nb + ni * 16 + ml;
            #pragma unroll
            for (int mi = 0; mi < 2; ++mi)
                #pragma unroll
                for (int v = 0; v < 4; ++v) {
                    int row = mi * 16 + q * 4 + v;
                    storeb[(outBase + row) * D_ + n] = f2bf(acc2[mi][ni][v] + bias2[ni]);
                }
        }
        grid_barrier(bar, 1 + l);
    }

    // ---- phase 7: eval ----
    {
        int wid = bid * 8 + w;
        const int nw = GRID_ * 8;
        float ew0 = eval_w[lane * 4 + 0], ew1 = eval_w[lane * 4 + 1];
        float ew2 = eval_w[lane * 4 + 2], ew3 = eval_w[lane * 4 + 3];
        float pw = pos_weight[0], eb = eval_b[0];
        float loss = 0, posTot = 0, negTot = 0, posOK = 0, negOK = 0;
        for (int node = wid; node < TOTAL_; node += nw) {
            ushort4 v = *(const ushort4*)(storeb + (size_t)node * D_ + lane * 4);
            float s = bf2f(v.x) * ew0 + bf2f(v.y) * ew1 + bf2f(v.z) * ew2 + bf2f(v.w) * ew3;
            #pragma unroll
            for (int off = 32; off > 0; off >>= 1) s += __shfl_down(s, off);
            if (lane == 0) {
                float x   = s + eb;
                float pos = pos_vals[node], neg = neg_vals[node];
                float tot = pos + neg;
                if (tot > 0.0f) {
                    float tgt = pos / fmaxf(tot, 1e-9f);
                    loss += tot * (pw * tgt * softplus_f(-x) + (1.0f - tgt) * softplus_f(x));
                    posTot += pos; negTot += neg;
                    if (x >= 0.0f) posOK += pos; else negOK += neg;
                }
            }
        }
        if (tid == 0) { for (int i = 0; i < 5; ++i) sh[i] = 0.0f; }
        __syncthreads();
        if (lane == 0) {
            atomicAdd(&sh[0], loss); atomicAdd(&sh[1], posTot); atomicAdd(&sh[2], negTot);
            atomicAdd(&sh[3], posOK); atomicAdd(&sh[4], negOK);
        }
        __syncthreads();
        if (tid < 5) atomicAdd(&accum[tid], sh[tid]);
    }
    grid_barrier(bar, 7);

    if (bid == 0 && tid == 0) {
        float loss = accum[0], posTot = accum[1], negTot = accum[2];
        float posOK = accum[3], negOK = accum[4];
        out[0] = loss;
        out[1] = (posTot > 0.0f) ? posOK / fmaxf(posTot, 1e-9f) : 1.0f;
        out[2] = (negTot > 0.0f) ? negOK / fmaxf(negTot, 1e-9f) : 1.0f;
    }
}

// ---------------------------------------------------------------- launch ---
extern "C" void kernel_launch(void* const* d_in, const int* in_sizes, int n_in,
                              void* d_out, int out_size, void* d_ws, size_t ws_size,
                              hipStream_t stream) {
    const int*   thax       = (const int*)  d_in[0];
    const int*   par        = (const int*)  d_in[1];
    const float* pos_vals   = (const float*)d_in[2];
    const float* neg_vals   = (const float*)d_in[3];
    const float* init_table = (const float*)d_in[4];
    const float* W1         = (const float*)d_in[5];
    const float* b1         = (const float*)d_in[6];
    const float* W2         = (const float*)d_in[7];
    const float* b2         = (const float*)d_in[8];
    const float* eval_w     = (const float*)d_in[9];
    const float* eval_b     = (const float*)d_in[10];
    const float* pos_weight = (const float*)d_in[11];
    float* out = (float*)d_out;

    char* ws = (char*)d_ws;
    unsigned short* w1img  = (unsigned short*)(ws);                            // 4 MB
    unsigned short* w2img  = (unsigned short*)(ws + (size_t)4  * 1024 * 1024); // 2 MB
    unsigned short* storeb = (unsigned short*)(ws + (size_t)6  * 1024 * 1024); // 28 MB
    float*          accum  = (float*)(ws + (size_t)6 * 1024 * 1024 +
                                      (size_t)TOTAL_ * D_ * 2);
    unsigned*       bar    = (unsigned*)(accum + 16);

    hipLaunchKernelGGL(wimg_k, dim3(R_ * 16), dim3(256), 0, stream,
                       W1, w1img, 16, accum, bar);
    hipLaunchKernelGGL(wimg_k, dim3(R_ * 8), dim3(256), 0, stream,
                       W2, w2img, 8, accum, bar);
    hipLaunchKernelGGL(fused_k, dim3(GRID_), dim3(512), 0, stream,
                       thax, init_table, storeb, par, w1img, w2img, b1, b2,
                       eval_w, eval_b, pos_vals, neg_vals, pos_weight,
                       accum, bar, out);
}

// Round 9
// 186.566 us; speedup vs baseline: 1.8021x; 1.8021x over previous
//
#include <hip/hip_runtime.h>
#include <cstdint>
#include <cstddef>

#define D_     256
#define TWO_D  512
#define R_     16
#define N0_    8192
#define L_     6
#define NL_    8192
#define B_     512
#define TOTAL_ (N0_ + L_*NL_)

#define MT      16          // nodes (M) per layer block -> 512 blocks, 2/CU
#define XPITCH  536         // ushort pitch; dword stride 268 = 12 mod 32 -> 2-way (free)
#define HPITCH  280         // ushort pitch; dword stride 140 = 12 mod 32
#define LGRID   512

using short8 = __attribute__((ext_vector_type(8))) short;   // 8 bf16 (4 VGPRs)
using f32x4  = __attribute__((ext_vector_type(4))) float;   // 4 fp32 acc

__device__ __forceinline__ unsigned short f2bf(float f) {
    union { float f; unsigned u; } v; v.f = f;
    unsigned u = v.u;
    return (unsigned short)((u + 0x7FFFu + ((u >> 16) & 1u)) >> 16);  // RNE
}
__device__ __forceinline__ float bf2f(unsigned short h) {
    union { unsigned u; float f; } v; v.u = ((unsigned)h) << 16;
    return v.f;
}
__device__ __forceinline__ float softplus_f(float x) {
    return fmaxf(x, 0.0f) + log1pf(expf(-fabsf(x)));
}

// ---------------------------------------------------------------- prep ----
// One kernel builds BOTH fragment images (coalesced reads via LDS tile):
// img(r,ks,q,n,j) = W[r][ks*32+q*8+j][n], laid out [r][ks][q][n][8] bf16.
// Block = one (r,ks) 32k x 256n tile. Also zeroes accum + done counter.
__global__ void wimg_k(const float* __restrict__ W1,
                       const float* __restrict__ W2,
                       unsigned short* __restrict__ w1img,
                       unsigned short* __restrict__ w2img,
                       float* __restrict__ accum,
                       unsigned* __restrict__ done) {
    if (blockIdx.x == 0 && threadIdx.x < 8) {
        accum[threadIdx.x] = 0.0f;
        if (threadIdx.x == 0) *done = 0u;
    }
    __shared__ unsigned short tile[32][264];    // +8 pad
    int bid = blockIdx.x;
    const float* src;
    unsigned short* dst;
    if (bid < 256) {                            // W1: r 0..15, ks 0..15
        int r = bid >> 4, ks = bid & 15;
        src = W1 + ((size_t)r * TWO_D + ks * 32) * 256;
        dst = w1img + (size_t)bid * 8192;       // (r*16+ks)*4*256*8
    } else {                                    // W2: r 0..15, ks 0..7
        int b = bid - 256;
        int r = b >> 3, ks = b & 7;
        src = W2 + ((size_t)r * D_ + ks * 32) * 256;
        dst = w2img + (size_t)b * 8192;
    }
    int t = threadIdx.x;
    // coalesced load 32 rows x 256 fp32 (8 float4/thread) -> bf16 tile
    #pragma unroll
    for (int it = 0; it < 8; ++it) {
        int idx = it * 256 + t;                 // 0..2047 = 32 rows x 64 f4
        int row = idx >> 6, c4 = (idx & 63) * 4;
        float4 v = *(const float4*)(src + (size_t)row * 256 + c4);
        tile[row][c4 + 0] = f2bf(v.x);
        tile[row][c4 + 1] = f2bf(v.y);
        tile[row][c4 + 2] = f2bf(v.z);
        tile[row][c4 + 3] = f2bf(v.w);
    }
    __syncthreads();
    // write fragments: item (q,n) -> 8 k's, coalesced 16B stores
    #pragma unroll
    for (int it = 0; it < 4; ++it) {
        int item = it * 256 + t;                // 0..1023 = 4q x 256n
        int q = item >> 8, n = item & 255;
        short8 v;
        #pragma unroll
        for (int j = 0; j < 8; ++j) v[j] = (short)tile[q * 8 + j][n];
        *(short8*)(dst + (size_t)item * 8) = v;
    }
}

// storeb[:N0] = bf16(init_table[thax])
__global__ void init_gather_k(const int* __restrict__ thax,
                              const float* __restrict__ table,
                              unsigned short* __restrict__ storeb) {
    int gid = blockIdx.x * 256 + threadIdx.x;
    int row = gid >> 6;
    int c   = (gid & 63) * 4;
    int t   = thax[row];
    float4 v = *(const float4*)(table + (size_t)t * D_ + c);
    ushort4 o;
    o.x = f2bf(v.x); o.y = f2bf(v.y); o.z = f2bf(v.z); o.w = f2bf(v.w);
    *(ushort4*)(storeb + (size_t)row * D_ + c) = o;
}

// ---------------------------------------------------------------- layer ----
// 512 blocks x 256 threads (4 waves; wave w owns n-slice [w*64,w*64+64)).
// Block = 16 nodes x full N=256 of one rule -> 2 blocks/CU: one block's
// gather/epilogue overlaps the other's GEMM phases (Amdahl fix). B-fragments
// from the coalesced image; rule<->XCD swizzle for L2 locality.
__global__ __launch_bounds__(256, 4)
void layer_k(unsigned short* __restrict__ storeb,
             const int* __restrict__ par,               // this layer: [NL][2]
             const unsigned short* __restrict__ w1img,  // [R][16][4][256][8]
             const unsigned short* __restrict__ w2img,  // [R][8][4][256][8]
             const float* __restrict__ b1,
             const float* __restrict__ b2,
             int layer) {
    __shared__ unsigned short X[MT * XPITCH];   // 17152 B (also out-stage)
    __shared__ unsigned short H[MT * HPITCH];   //  8960 B

    int bid = blockIdx.x;
    int r   = (bid & 7) | (((bid >> 3) & 1) << 3);   // XCD-local rule
    int mt  = bid >> 4;                               // 0..31
    int tid = threadIdx.x;
    int nodeInLayer0 = r * B_ + mt * MT;

    int w    = tid >> 6;        // wave 0..3 -> n-slice base w*64
    int lane = tid & 63;
    int q    = lane >> 4;
    int ml   = lane & 15;
    int nb   = w * 64;

    const unsigned short* w1r = w1img + (size_t)r * 16 * 8192;
    const unsigned short* w2r = w2img + (size_t)r * 8 * 8192;
    size_t fb = (size_t)(q * 256 + nb + ml) * 8;   // per-lane fragment base

    // gather parents -> X: 16 rows x 2 parents x 32 chunks = 1024, 4/thread
    int pidx[4];
    #pragma unroll
    for (int it = 0; it < 4; ++it) {
        int c = it * 256 + tid;
        pidx[it] = par[(nodeInLayer0 + (c >> 6)) * 2 + ((c & 63) >> 5)];
    }
    #pragma unroll
    for (int it = 0; it < 4; ++it) {
        int c   = it * 256 + tid;
        int m   = c >> 6;
        int rem = c & 63;
        int j   = rem >> 5;
        int c16 = rem & 31;
        uint4 v = *((const uint4*)(storeb + (size_t)pidx[it] * D_) + c16);
        *((uint4*)(&X[m * XPITCH + j * D_ + c16 * 8])) = v;
    }
    __syncthreads();

    // ---- GEMM1: [16 x 512] @ [512 x 256] -> H, relu(.+b1) ----
    f32x4 acc[4] = {};
    #pragma unroll
    for (int ks = 0; ks < 16; ++ks) {
        int k0 = ks * 32 + q * 8;
        short8 a = *(const short8*)(&X[ml * XPITCH + k0]);
        #pragma unroll
        for (int ni = 0; ni < 4; ++ni) {
            short8 b = *(const short8*)(&w1r[(size_t)ks * 8192 + fb + ni * 128]);
            acc[ni] = __builtin_amdgcn_mfma_f32_16x16x32_bf16(a, b, acc[ni], 0, 0, 0);
        }
    }
    #pragma unroll
    for (int ni = 0; ni < 4; ++ni) {
        int n = nb + ni * 16 + ml;
        float bias = b1[r * D_ + n];
        #pragma unroll
        for (int v = 0; v < 4; ++v) {
            int row = q * 4 + v;                 // C/D: row = quad*4+reg
            float x = acc[ni][v] + bias;
            H[row * HPITCH + n] = f2bf(x > 0.0f ? x : 0.0f);
        }
    }
    __syncthreads();

    // ---- GEMM2: [16 x 256] @ [256 x 256] (+b2) ----
    f32x4 acc2[4] = {};
    #pragma unroll
    for (int ks = 0; ks < 8; ++ks) {
        int k0 = ks * 32 + q * 8;
        short8 a = *(const short8*)(&H[ml * HPITCH + k0]);
        #pragma unroll
        for (int ni = 0; ni < 4; ++ni) {
            short8 b = *(const short8*)(&w2r[(size_t)ks * 8192 + fb + ni * 128]);
            acc2[ni] = __builtin_amdgcn_mfma_f32_16x16x32_bf16(a, b, acc2[ni], 0, 0, 0);
        }
    }
    // X reads done (pre-GEMM2 barrier) -> reuse X as out-stage
    #pragma unroll
    for (int ni = 0; ni < 4; ++ni) {
        int n = nb + ni * 16 + ml;
        float bias = b2[r * D_ + n];
        #pragma unroll
        for (int v = 0; v < 4; ++v) {
            int row = q * 4 + v;
            X[row * XPITCH + n] = f2bf(acc2[ni][v] + bias);
        }
    }
    __syncthreads();
    // coalesced store: 16 rows x 512 B, 2 uint4 per thread
    size_t outBase = (size_t)(N0_ + layer * NL_ + nodeInLayer0);
    #pragma unroll
    for (int it = 0; it < 2; ++it) {
        int c   = it * 256 + tid;       // 0..511 = 16 rows x 32 chunks
        int m   = c >> 5;
        int c16 = c & 31;
        uint4 v = *((const uint4*)(&X[m * XPITCH]) + c16);
        *((uint4*)(storeb + (outBase + m) * D_) + c16) = v;
    }
}

// ------------------------------------------------------------ eval+final --
__global__ void eval_k(const unsigned short* __restrict__ storeb,
                       const float* __restrict__ eval_w,
                       const float* __restrict__ eval_b,
                       const float* __restrict__ pos_vals,
                       const float* __restrict__ neg_vals,
                       const float* __restrict__ pos_weight,
                       float* __restrict__ accum,
                       unsigned* __restrict__ done,
                       float* __restrict__ out) {
    int lane = threadIdx.x & 63;
    int w    = threadIdx.x >> 6;
    int wid  = blockIdx.x * 4 + w;
    const int nw = 512 * 4;
    float ew0 = eval_w[lane * 4 + 0], ew1 = eval_w[lane * 4 + 1];
    float ew2 = eval_w[lane * 4 + 2], ew3 = eval_w[lane * 4 + 3];
    float pw = pos_weight[0], eb = eval_b[0];
    float loss = 0, posTot = 0, negTot = 0, posOK = 0, negOK = 0;

    for (int node = wid; node < TOTAL_; node += nw) {
        ushort4 v = *(const ushort4*)(storeb + (size_t)node * D_ + lane * 4);
        float s = bf2f(v.x) * ew0 + bf2f(v.y) * ew1 + bf2f(v.z) * ew2 + bf2f(v.w) * ew3;
        #pragma unroll
        for (int off = 32; off > 0; off >>= 1) s += __shfl_down(s, off);
        if (lane == 0) {
            float x   = s + eb;
            float pos = pos_vals[node], neg = neg_vals[node];
            float tot = pos + neg;
            if (tot > 0.0f) {
                float tgt = pos / fmaxf(tot, 1e-9f);
                loss += tot * (pw * tgt * softplus_f(-x) + (1.0f - tgt) * softplus_f(x));
                posTot += pos; negTot += neg;
                if (x >= 0.0f) posOK += pos; else negOK += neg;
            }
        }
    }
    __shared__ float sh[5];
    __shared__ bool amLast;
    if (threadIdx.x == 0) { for (int i = 0; i < 5; ++i) sh[i] = 0.0f; }
    __syncthreads();
    if (lane == 0) {
        atomicAdd(&sh[0], loss); atomicAdd(&sh[1], posTot); atomicAdd(&sh[2], negTot);
        atomicAdd(&sh[3], posOK); atomicAdd(&sh[4], negOK);
    }
    __syncthreads();
    if (threadIdx.x < 5) atomicAdd(&accum[threadIdx.x], sh[threadIdx.x]);
    // last-block finalize (done-ticket)
    if (threadIdx.x == 0) {
        __threadfence();
        unsigned t = atomicAdd(done, 1u);
        amLast = (t == 512u - 1u);
    }
    __syncthreads();
    if (amLast && threadIdx.x == 0) {
        float a0 = __hip_atomic_load(&accum[0], __ATOMIC_RELAXED, __HIP_MEMORY_SCOPE_AGENT);
        float a1 = __hip_atomic_load(&accum[1], __ATOMIC_RELAXED, __HIP_MEMORY_SCOPE_AGENT);
        float a2 = __hip_atomic_load(&accum[2], __ATOMIC_RELAXED, __HIP_MEMORY_SCOPE_AGENT);
        float a3 = __hip_atomic_load(&accum[3], __ATOMIC_RELAXED, __HIP_MEMORY_SCOPE_AGENT);
        float a4 = __hip_atomic_load(&accum[4], __ATOMIC_RELAXED, __HIP_MEMORY_SCOPE_AGENT);
        out[0] = a0;
        out[1] = (a1 > 0.0f) ? a3 / fmaxf(a1, 1e-9f) : 1.0f;
        out[2] = (a2 > 0.0f) ? a4 / fmaxf(a2, 1e-9f) : 1.0f;
    }
}

// ---------------------------------------------------------------- launch ---
extern "C" void kernel_launch(void* const* d_in, const int* in_sizes, int n_in,
                              void* d_out, int out_size, void* d_ws, size_t ws_size,
                              hipStream_t stream) {
    const int*   thax       = (const int*)  d_in[0];
    const int*   par        = (const int*)  d_in[1];
    const float* pos_vals   = (const float*)d_in[2];
    const float* neg_vals   = (const float*)d_in[3];
    const float* init_table = (const float*)d_in[4];
    const float* W1         = (const float*)d_in[5];
    const float* b1         = (const float*)d_in[6];
    const float* W2         = (const float*)d_in[7];
    const float* b2         = (const float*)d_in[8];
    const float* eval_w     = (const float*)d_in[9];
    const float* eval_b     = (const float*)d_in[10];
    const float* pos_weight = (const float*)d_in[11];
    float* out = (float*)d_out;

    char* ws = (char*)d_ws;
    unsigned short* w1img  = (unsigned short*)(ws);                            // 4 MB
    unsigned short* w2img  = (unsigned short*)(ws + (size_t)4  * 1024 * 1024); // 2 MB
    unsigned short* storeb = (unsigned short*)(ws + (size_t)6  * 1024 * 1024); // 28 MB
    float*          accum  = (float*)(ws + (size_t)6 * 1024 * 1024 +
                                      (size_t)TOTAL_ * D_ * 2);
    unsigned*       done   = (unsigned*)(accum + 8);

    hipLaunchKernelGGL(wimg_k, dim3(384), dim3(256), 0, stream,
                       W1, W2, w1img, w2img, accum, done);
    hipLaunchKernelGGL(init_gather_k, dim3(N0_ * 64 / 256), dim3(256), 0, stream,
                       thax, init_table, storeb);
    for (int l = 0; l < L_; ++l) {
        hipLaunchKernelGGL(layer_k, dim3(LGRID), dim3(256), 0, stream,
                           storeb, par + (size_t)l * NL_ * 2, w1img, w2img, b1, b2, l);
    }
    hipLaunchKernelGGL(eval_k, dim3(512), dim3(256), 0, stream,
                       storeb, eval_w, eval_b, pos_vals, neg_vals, pos_weight,
                       accum, done, out);
}